// Round 4
// baseline (638.465 us; speedup 1.0000x reference)
//
#include <hip/hip_runtime.h>

// FillSimNet: 4-layer GCN forward.
//   1. packed u64 atomics: hi32 = in-degree count, lo32 = fixed-point (2^24) weight sum
//   2. block-scan -> row_ptr, fill CSR (by dst) with packed (col, norm) int2
//   3. encoder MLP (8->64 relu 64->64)
//   4. 4x fused layer: agg = SpMM(norm, h); h = relu(agg @ W + b)
//      gather loop: 8 inline-asm global_load_dwordx4 in flight per 16-lane group,
//      single manual s_waitcnt vmcnt(0) -> real memory-level parallelism
//   5. decoder MLP (64->64 relu 64->1)

constexpr int NN   = 100000;
constexpr int NE   = 1600000;
constexpr int INPD = 8;
constexpr int EMBD = 64;
constexpr int NLAY = 4;
constexpr int SCAN_B = 1024;
constexpr int SCAN_NBLK = (NN + SCAN_B - 1) / SCAN_B; // 98
constexpr float FPSCALE = 16777216.0f;   // 2^24
constexpr int LNODES = 32;               // nodes per k_layer block (512 threads)

typedef float f32x4 __attribute__((ext_vector_type(4)));

__global__ void k_init(unsigned long long* packed) {
    int i = blockIdx.x * blockDim.x + threadIdx.x;
    if (i < NN) packed[i] = (unsigned long long)(1u << 24);  // self-loop weight 1.0, count 0
}

__global__ void k_count(const int* __restrict__ ei, const float* __restrict__ w,
                        unsigned long long* __restrict__ packed) {
    int e = blockIdx.x * blockDim.x + threadIdx.x;
    if (e < NE) {
        int d = ei[NE + e];
        unsigned int fx = (unsigned int)(w[e] * FPSCALE + 0.5f);
        atomicAdd(&packed[d], (1ull << 32) | (unsigned long long)fx);
    }
}

__global__ __launch_bounds__(SCAN_B) void k_scan1(const unsigned long long* __restrict__ packed,
                                                  int* incl, int* partials) {
    __shared__ int s[SCAN_B];
    int tid = threadIdx.x;
    int i = blockIdx.x * SCAN_B + tid;
    int v = (i < NN) ? (int)(packed[i] >> 32) : 0;
    s[tid] = v;
    __syncthreads();
    for (int off = 1; off < SCAN_B; off <<= 1) {
        int t = (tid >= off) ? s[tid - off] : 0;
        __syncthreads();
        s[tid] += t;
        __syncthreads();
    }
    if (i < NN) incl[i] = s[tid];
    if (tid == SCAN_B - 1) partials[blockIdx.x] = s[tid];
}

__global__ void k_scan2(int* partials) {
    if (threadIdx.x == 0 && blockIdx.x == 0) {
        int run = 0;
        for (int b = 0; b < SCAN_NBLK; ++b) {
            int t = partials[b];
            partials[b] = run;
            run += t;
        }
        partials[SCAN_NBLK] = run;  // == NE
    }
}

// also computes dis = 1/sqrt(deg)
__global__ void k_scan3(const unsigned long long* __restrict__ packed,
                        const int* __restrict__ incl, const int* __restrict__ partials,
                        int* row_ptr, int* cursor, float* __restrict__ dis) {
    int i = blockIdx.x * blockDim.x + threadIdx.x;
    if (i < NN) {
        unsigned long long p = packed[i];
        int c = (int)(p >> 32);
        int rp = incl[i] - c + partials[i >> 10];
        row_ptr[i] = rp;
        cursor[i] = rp;
        float deg = (float)(unsigned int)(p & 0xffffffffull) * (1.0f / FPSCALE);
        dis[i] = 1.0f / sqrtf(deg);   // deg >= 1 always
        if (i == 0) row_ptr[NN] = partials[SCAN_NBLK];
    }
}

__global__ void k_fill(const int* __restrict__ ei, const float* __restrict__ w,
                       const float* __restrict__ dis,
                       int* __restrict__ cursor, int2* __restrict__ edges) {
    int e = blockIdx.x * blockDim.x + threadIdx.x;
    if (e < NE) {
        int s = ei[e];
        int d = ei[NE + e];
        int pos = atomicAdd(&cursor[d], 1);
        float nv = dis[s] * w[e] * dis[d];
        edges[pos] = make_int2(s, __float_as_int(nv));
    }
}

// encoder: h = relu(x@W1+b1)@W2 + b2 ; 16 nodes per 256-thread block
__global__ __launch_bounds__(256) void k_encoder(const float* __restrict__ x,
                                                 const float* __restrict__ w1,
                                                 const float* __restrict__ b1,
                                                 const float* __restrict__ w2,
                                                 const float* __restrict__ b2,
                                                 float* __restrict__ h) {
    __shared__ float sW1[INPD * EMBD];
    __shared__ float sW2[EMBD * EMBD];
    __shared__ float sB1[EMBD];
    __shared__ float sB2[EMBD];
    __shared__ float sZ[16][EMBD];
    int tid = threadIdx.x;
    for (int i = tid; i < INPD * EMBD; i += 256) sW1[i] = w1[i];
    for (int i = tid; i < EMBD * EMBD; i += 256) sW2[i] = w2[i];
    if (tid < EMBD) { sB1[tid] = b1[tid]; sB2[tid] = b2[tid]; }
    __syncthreads();
    int base = blockIdx.x * 16;
    #pragma unroll
    for (int it = 0; it < 4; ++it) {
        int item = tid + it * 256;
        int nl = item >> 6, j = item & 63;
        int node = base + nl;
        float acc = sB1[j];
        if (node < NN) {
            const float* xr = x + (size_t)node * INPD;
            #pragma unroll
            for (int k = 0; k < INPD; ++k) acc += xr[k] * sW1[k * EMBD + j];
        }
        sZ[nl][j] = fmaxf(acc, 0.0f);
    }
    __syncthreads();
    #pragma unroll
    for (int it = 0; it < 4; ++it) {
        int item = tid + it * 256;
        int nl = item >> 6, j2 = item & 63;
        int node = base + nl;
        if (node < NN) {
            float acc = sB2[j2];
            for (int j = 0; j < EMBD; ++j) acc += sZ[nl][j] * sW2[j * EMBD + j2];
            h[(size_t)node * EMBD + j2] = acc;
        }
    }
}

// fused layer: agg = dis[n]^2*h[n] + sum_e norm[e]*h[col[e]] ; hout = relu(agg @ W + b)
// 32 nodes / 512-thread block; 16 lanes per node; 8 asm gathers in flight per batch
__global__ __launch_bounds__(512) void k_layer(const float* __restrict__ hin,
                                               const float* __restrict__ dis,
                                               const int* __restrict__ row_ptr,
                                               const int2* __restrict__ edges,
                                               const float* __restrict__ W,
                                               const float* __restrict__ bias,
                                               float* __restrict__ hout) {
    __shared__ float sW[EMBD * EMBD];
    __shared__ float sB[EMBD];
    __shared__ float sA[LNODES][EMBD];
    int tid = threadIdx.x;
    for (int i = tid; i < EMBD * EMBD; i += 512) sW[i] = W[i];
    if (tid < EMBD) sB[tid] = bias[tid];

    int g = tid >> 4, l = tid & 15;
    int node = blockIdx.x * LNODES + g;
    const f32x4* h4 = (const f32x4*)hin;
    f32x4 acc0 = (f32x4)(0.f), acc1 = (f32x4)(0.f);
    if (node < NN) {
        float dsn = dis[node];
        float sn = dsn * dsn;
        f32x4 self = h4[(size_t)node * 16 + l];
        acc0 = sn * self;
        int beg = row_ptr[node], end = row_ptr[node + 1];
        int e = beg;
        for (; e + 8 <= end; e += 8) {
            int2 m[8];
            #pragma unroll
            for (int u = 0; u < 8; ++u) m[u] = edges[e + u];
            f32x4 t[8];
            #pragma unroll
            for (int u = 0; u < 8; ++u) {
                const f32x4* p = h4 + ((size_t)m[u].x * 16 + l);
                asm volatile("global_load_dwordx4 %0, %1, off"
                             : "=v"(t[u]) : "v"(p) : "memory");
            }
            asm volatile("s_waitcnt vmcnt(0)" ::: "memory");
            __builtin_amdgcn_sched_barrier(0);
            #pragma unroll
            for (int u = 0; u < 8; ++u) {
                float v = __int_as_float(m[u].y);
                if (u & 1) acc1 += v * t[u];
                else       acc0 += v * t[u];
            }
        }
        for (; e < end; ++e) {
            int2 ev = edges[e];
            float v = __int_as_float(ev.y);
            acc0 += v * h4[(size_t)ev.x * 16 + l];
        }
    }
    acc0 += acc1;
    ((f32x4*)&sA[g][0])[l] = acc0;
    __syncthreads();

    int base = blockIdx.x * LNODES;
    #pragma unroll
    for (int it = 0; it < 4; ++it) {
        int item = tid + it * 512;
        int nl = item >> 6, j2 = item & 63;
        int onode = base + nl;
        if (onode < NN) {
            float o = sB[j2];
            for (int k = 0; k < EMBD; ++k) o += sA[nl][k] * sW[k * EMBD + j2];
            hout[(size_t)onode * EMBD + j2] = fmaxf(o, 0.0f);
        }
    }
}

// out = relu(h@W1+b1)@W2 + b2 (OUT=1) ; one wave per node, 4 nodes/wave serial
__global__ __launch_bounds__(256) void k_decoder(const float* __restrict__ h,
                                                 const float* __restrict__ w1,
                                                 const float* __restrict__ b1,
                                                 const float* __restrict__ w2,
                                                 const float* __restrict__ b2,
                                                 float* __restrict__ out) {
    __shared__ float sW1[EMBD * EMBD];
    __shared__ float sB1[EMBD];
    __shared__ float sW2[EMBD];
    int tid = threadIdx.x;
    for (int i = tid; i < EMBD * EMBD; i += 256) sW1[i] = w1[i];
    if (tid < EMBD) { sB1[tid] = b1[tid]; sW2[tid] = w2[tid]; }
    __syncthreads();
    int wave = tid >> 6, lane = tid & 63;
    float db2 = b2[0];
    #pragma unroll
    for (int it = 0; it < 4; ++it) {
        int node = blockIdx.x * 16 + wave * 4 + it;
        if (node >= NN) continue;
        const float* hr = h + (size_t)node * EMBD;
        float acc = sB1[lane];
        for (int k = 0; k < EMBD; ++k) acc += hr[k] * sW1[k * EMBD + lane];
        acc = fmaxf(acc, 0.0f);
        float r = acc * sW2[lane];
        for (int o = 32; o > 0; o >>= 1) r += __shfl_down(r, o);
        if (lane == 0) out[node] = r + db2;
    }
}

extern "C" void kernel_launch(void* const* d_in, const int* in_sizes, int n_in,
                              void* d_out, int out_size, void* d_ws, size_t ws_size,
                              hipStream_t stream) {
    const float* x      = (const float*)d_in[0];
    const int*   ei     = (const int*)  d_in[1];
    const float* ew     = (const float*)d_in[2];
    const float* enc_w1 = (const float*)d_in[3];
    const float* enc_b1 = (const float*)d_in[4];
    const float* enc_w2 = (const float*)d_in[5];
    const float* enc_b2 = (const float*)d_in[6];
    const float* gcn_w  = (const float*)d_in[7];
    const float* gcn_b  = (const float*)d_in[8];
    const float* dec_w1 = (const float*)d_in[9];
    const float* dec_b1 = (const float*)d_in[10];
    const float* dec_w2 = (const float*)d_in[11];
    const float* dec_b2 = (const float*)d_in[12];
    float* out = (float*)d_out;

    char* ws = (char*)d_ws;
    size_t off = 0;
    auto alloc = [&](size_t bytes) -> void* {
        void* p = (void*)(ws + off);
        off += (bytes + 511) & ~(size_t)511;
        return p;
    };
    unsigned long long* packed = (unsigned long long*)alloc((size_t)NN * 8);
    float* dis      = (float*)alloc(NN * 4);
    int*   incl     = (int*)  alloc(NN * 4);
    int*   partials = (int*)  alloc(256 * 4);
    int*   row_ptr  = (int*)  alloc((NN + 1) * 4);
    int*   cursor   = (int*)  alloc(NN * 4);
    int2*  edges    = (int2*) alloc((size_t)NE * 8);
    float* hbuf     = (float*)alloc((size_t)NN * EMBD * 4);
    float* hbuf2    = (float*)alloc((size_t)NN * EMBD * 4);
    (void)ws_size; (void)n_in; (void)in_sizes; (void)out_size;

    int gN   = (NN + 255) / 256;
    int gE   = (NE + 255) / 256;
    int gT16 = (NN + 15) / 16;
    int gL   = (NN + LNODES - 1) / LNODES;

    k_init<<<gN, 256, 0, stream>>>(packed);
    k_count<<<gE, 256, 0, stream>>>(ei, ew, packed);
    k_scan1<<<SCAN_NBLK, SCAN_B, 0, stream>>>(packed, incl, partials);
    k_scan2<<<1, 1, 0, stream>>>(partials);
    k_scan3<<<gN, 256, 0, stream>>>(packed, incl, partials, row_ptr, cursor, dis);
    k_fill<<<gE, 256, 0, stream>>>(ei, ew, dis, cursor, edges);

    k_encoder<<<gT16, 256, 0, stream>>>(x, enc_w1, enc_b1, enc_w2, enc_b2, hbuf);

    float* cur = hbuf;
    float* nxt = hbuf2;
    for (int layer = 0; layer < NLAY; ++layer) {
        k_layer<<<gL, 512, 0, stream>>>(cur, dis, row_ptr, edges,
                                        gcn_w + (size_t)layer * EMBD * EMBD,
                                        gcn_b + (size_t)layer * EMBD, nxt);
        float* tmp = cur; cur = nxt; nxt = tmp;
    }

    k_decoder<<<gT16, 256, 0, stream>>>(cur, dec_w1, dec_b1, dec_w2, dec_b2, out);
}